// Round 5
// baseline (189.646 us; speedup 1.0000x reference)
//
#include <hip/hip_runtime.h>
#include <math.h>

// StickBreakingVAE forward, bf16-MFMA + global_load_lds + 2-phase LDS double-buffer.
// B=32768, D=784, H=500, K=50.
// cast_x: x f32 [B,784] -> xb bf16 [B,832]   (xb lives in d_out recon scratch)
// GEMM1: h   = relu(xb @ enc_w1 + b)     K=832 N=512  (bf16, ws)
// GEMM2/3:   [alpha|beta] = softplus(h @ wab + b)  K=512 N=128 (f32 -> d_out)
// sample_pi: wave-per-row stick-breaking scan -> pib bf16 [B,64] (ws)
// GEMM4: hd  = relu(pib @ dec_w1 + b)    K=64  N=512  (bf16, reuses h region)
// GEMM5: rec = sigmoid(hd @ dec_w2 + b)  K=512 N=896  (f32 masked -> d_out, over xb)

typedef __bf16 bf16x8 __attribute__((ext_vector_type(8)));
typedef float f32x4 __attribute__((ext_vector_type(4)));

#define BATCH 32768
#define BM 128
#define BN 128
#define BK 64

__device__ __forceinline__ unsigned short bf16_bits(float f) {
    __bf16 b = (__bf16)f;
    return __builtin_bit_cast(unsigned short, b);
}

__device__ __forceinline__ void gll16(const unsigned short* src, unsigned short* ldsdst) {
    __builtin_amdgcn_global_load_lds(
        (const __attribute__((address_space(1))) unsigned int*)src,
        (__attribute__((address_space(3))) unsigned int*)ldsdst,
        16, 0, 0);
}

// MODE 0: relu -> bf16 C [ldc], full padded tile stored
// MODE 1: softplus -> alpha (gn<50) / beta (50<=gn<100) f32 compact [B,50] each
// MODE 2: sigmoid -> f32 C [B,Nreal], store only gn < Nreal
template<int MODE>
__global__ __launch_bounds__(256) void mfma_gemm(
    const unsigned short* __restrict__ A,   // [M][lda] bf16 (zero-padded)
    const unsigned short* __restrict__ Bt,  // [Npad][Kpad] bf16 (zero-padded)
    const float* __restrict__ bias,         // [Npad]
    void* __restrict__ Cv,
    int Kpad, int lda, int ldc, int Nreal, int nbx)
{
    __shared__ unsigned short As[2][BM * BK];   // double-buffered; linear row*64+g*8
    __shared__ unsigned short Bs[2][BN * BK];

    // ---- chunked bijective XCD swizzle (T1, m204): same-A-panel blocks -> same XCD L2
    const int nwg = gridDim.x;
    const int orig = blockIdx.x;
    const int q = nwg >> 3, r8 = nwg & 7;
    const int xcd = orig & 7;
    const int chunkbase = (xcd < r8) ? xcd * (q + 1) : r8 * (q + 1) + (xcd - r8) * q;
    const int wgid = chunkbase + (orig >> 3);
    const int bn = wgid % nbx;               // n fastest within chunk -> A-panel L2 reuse
    const size_t block_m = (size_t)(wgid / nbx) * BM;
    const int block_n = bn * BN;

    const int tid = threadIdx.x;
    const int l = tid & 63;
    const int wid = tid >> 6;
    const int wr = wid >> 1, wc = wid & 1;

    const int lr = l & 15;   // fragment row-in-16
    const int kh = l >> 4;   // fragment k-granule (0..3)

    f32x4 acc[4][4] = {};

    // stage one K-tile into buffer `buf`: linear LDS dest (wave-uniform base+lane*16),
    // global source granule XOR-pre-swizzled so the swizzled ds_read is conflict-free
    auto stage = [&](int buf, int k0) {
        #pragma unroll
        for (int i = 0; i < 4; ++i) {
            int chunk = wid * 4 + i;          // 16 chunks of 1KB each
            int gid = chunk * 64 + l;         // granule id 0..1023
            int r = gid >> 3;                 // tile row 0..127
            int kgs = (gid & 7) ^ (r & 7);    // swizzled source granule
            gll16(A + (block_m + r) * (size_t)lda + k0 + kgs * 8, &As[buf][chunk * 512]);
            gll16(Bt + (size_t)(block_n + r) * Kpad + k0 + kgs * 8, &Bs[buf][chunk * 512]);
        }
    };

    auto compute = [&](int buf) {
        #pragma unroll
        for (int s = 0; s < 2; ++s) {
            bf16x8 af[4], bf[4];
            #pragma unroll
            for (int mi = 0; mi < 4; ++mi) {
                int row = wr * 64 + mi * 16 + lr;
                int g = (s * 4 + kh) ^ (row & 7);
                af[mi] = *(const bf16x8*)(&As[buf][row * 64 + g * 8]);
            }
            #pragma unroll
            for (int ni = 0; ni < 4; ++ni) {
                int row = wc * 64 + ni * 16 + lr;
                int g = (s * 4 + kh) ^ (row & 7);
                bf[ni] = *(const bf16x8*)(&Bs[buf][row * 64 + g * 8]);
            }
            #pragma unroll
            for (int mi = 0; mi < 4; ++mi)
                #pragma unroll
                for (int ni = 0; ni < 4; ++ni)
                    acc[mi][ni] = __builtin_amdgcn_mfma_f32_16x16x32_bf16(
                        af[mi], bf[ni], acc[mi][ni], 0, 0, 0);
        }
    };

    const int nt = Kpad / BK;
    // prologue
    stage(0, 0);
    asm volatile("s_waitcnt vmcnt(0)" ::: "memory");
    __syncthreads();
    int cur = 0;
    // 2-phase pipelined main loop: issue next-tile loads BEFORE computing current
    for (int t = 0; t < nt - 1; ++t) {
        stage(cur ^ 1, (t + 1) * BK);
        compute(cur);
        asm volatile("s_waitcnt vmcnt(0)" ::: "memory");
        __syncthreads();
        cur ^= 1;
    }
    compute(cur);

    // epilogue: C/D layout col=lane&15, row=(lane>>4)*4+j
    const int rg = (l >> 4) * 4;
    #pragma unroll
    for (int mi = 0; mi < 4; ++mi) {
        #pragma unroll
        for (int ni = 0; ni < 4; ++ni) {
            int gn = block_n + wc * 64 + ni * 16 + lr;
            float bs = bias[gn];
            #pragma unroll
            for (int j = 0; j < 4; ++j) {
                long gm = block_m + wr * 64 + mi * 16 + rg + j;
                float z = acc[mi][ni][j] + bs;
                if (MODE == 0) {
                    z = fmaxf(z, 0.f);
                    ((unsigned short*)Cv)[gm * ldc + gn] = bf16_bits(z);
                } else if (MODE == 1) {
                    z = (z > 0.f) ? z + __logf(1.f + __expf(-z))
                                  : __logf(1.f + __expf(z));
                    float* out = (float*)Cv;
                    if (gn < 50)       out[gm * 50 + gn] = z;
                    else if (gn < 100) out[(size_t)BATCH * 50 + gm * 50 + (gn - 50)] = z;
                } else {
                    if (gn < Nreal) {
                        z = (z >= 0.f) ? 1.f / (1.f + __expf(-z))
                                       : __expf(z) / (1.f + __expf(z));
                        ((float*)Cv)[gm * Nreal + gn] = z;
                    }
                }
            }
        }
    }
}

// x f32 [B][784] -> xb bf16 [B][832] zero-padded
__global__ __launch_bounds__(256) void cast_x(
    const float* __restrict__ x, unsigned short* __restrict__ xb)
{
    int gid = blockIdx.x * 256 + threadIdx.x;   // granule of 8 elems; B*104 total
    int r = gid / 104;
    int c = gid - r * 104;
    union { __bf16 b[8]; uint4 u; } pk;
    if (c < 98) {
        const float4* p = (const float4*)(x + (size_t)r * 784 + c * 8);
        float4 f0 = p[0], f1 = p[1];
        pk.b[0] = (__bf16)f0.x; pk.b[1] = (__bf16)f0.y;
        pk.b[2] = (__bf16)f0.z; pk.b[3] = (__bf16)f0.w;
        pk.b[4] = (__bf16)f1.x; pk.b[5] = (__bf16)f1.y;
        pk.b[6] = (__bf16)f1.z; pk.b[7] = (__bf16)f1.w;
    } else {
        pk.u = make_uint4(0, 0, 0, 0);
    }
    *(uint4*)(xb + (size_t)r * 832 + c * 8) = pk.u;
}

// weight [Kr][Nr] f32 -> [Npad][Kpad] bf16 transposed, bias padded
__global__ __launch_bounds__(256) void prep_bt(
    const float* __restrict__ W, const float* __restrict__ bias,
    unsigned short* __restrict__ Bt, float* __restrict__ bpad,
    int Kr, int Nr, int Kpad, int Npad)
{
    int idx = blockIdx.x * 256 + threadIdx.x;
    if (idx >= Npad * Kpad) return;
    int n = idx / Kpad, k = idx - n * Kpad;
    float v = (n < Nr && k < Kr) ? W[(size_t)k * Nr + n] : 0.f;
    Bt[idx] = bf16_bits(v);
    if (k == 0) bpad[n] = (n < Nr) ? bias[n] : 0.f;
}

// [w_alpha | w_beta] -> [128][512] bf16 transposed
__global__ __launch_bounds__(256) void prep_wab(
    const float* __restrict__ Wa, const float* __restrict__ Wb,
    const float* __restrict__ ba, const float* __restrict__ bb,
    unsigned short* __restrict__ Bt, float* __restrict__ bpad)
{
    int idx = blockIdx.x * 256 + threadIdx.x;
    if (idx >= 128 * 512) return;
    int n = idx >> 9, k = idx & 511;
    float v = 0.f;
    if (k < 500) {
        if (n < 50)       v = Wa[(size_t)k * 50 + n];
        else if (n < 100) v = Wb[(size_t)k * 50 + (n - 50)];
    }
    Bt[idx] = bf16_bits(v);
    if (k == 0) bpad[n] = (n < 50) ? ba[n] : ((n < 100) ? bb[n - 50] : 0.f);
}

// Kumaraswamy sample + stick-breaking. One WAVE per row: lane k computes v_k,
// then 6-step shuffle prefix-product scan replaces the serial cumprod.
__global__ __launch_bounds__(256) void sample_pi(
    const float* __restrict__ u, const float* __restrict__ alpha,
    const float* __restrict__ beta, unsigned short* __restrict__ pib)
{
    int row = (blockIdx.x * 256 + threadIdx.x) >> 6;   // wave index = row
    int lane = threadIdx.x & 63;
    size_t base = (size_t)row * 50;

    float v = 0.f, w = 1.f;
    if (lane < 50) {
        float a = alpha[base + lane];
        float b = beta[base + lane];
        float uu = u[base + lane];
        float t = exp2f(__fdividef(log2f(uu), b));          // u^(1/beta)
        v = exp2f(__fdividef(log2f(1.f - t), a));           // (1-t)^(1/alpha)
        w = 1.f - v;
    }
    // inclusive prefix product of w across the wave
    float p = w;
    #pragma unroll
    for (int off = 1; off < 64; off <<= 1) {
        float t = __shfl_up(p, off, 64);
        if (lane >= off) p *= t;
    }
    // exclusive scan -> pi = v * prod_{j<k}(1-v_j)
    float ex = __shfl_up(p, 1, 64);
    if (lane == 0) ex = 1.f;
    float pi = v * ex;
    pib[(size_t)row * 64 + lane] = (lane < 50) ? bf16_bits(pi) : (unsigned short)0;
}

extern "C" void kernel_launch(void* const* d_in, const int* in_sizes, int n_in,
                              void* d_out, int out_size, void* d_ws, size_t ws_size,
                              hipStream_t stream) {
    const float* x       = (const float*)d_in[0];
    const float* u       = (const float*)d_in[1];
    const float* enc_w1  = (const float*)d_in[2];
    const float* enc_b1  = (const float*)d_in[3];
    const float* w_alpha = (const float*)d_in[4];
    const float* b_alpha = (const float*)d_in[5];
    const float* w_beta  = (const float*)d_in[6];
    const float* b_beta  = (const float*)d_in[7];
    const float* dec_w1  = (const float*)d_in[8];
    const float* dec_b1  = (const float*)d_in[9];
    const float* dec_w2  = (const float*)d_in[10];
    const float* dec_b2  = (const float*)d_in[11];

    const int D = 784;

    float* out   = (float*)d_out;
    float* recon = out;                              // [B,784] f32
    float* alpha = out + (size_t)BATCH * D;          // [B,50]; beta at +B*50

    // xb scratch lives in the recon region (dead until GEMM5)
    unsigned short* xb = (unsigned short*)d_out;     // [B][832] bf16

    // workspace layout
    char* ws = (char*)d_ws;
    unsigned short* w1b  = (unsigned short*)(ws);             // 512*832*2 = 851968
    unsigned short* wab  = (unsigned short*)(ws + 851968);    // 128*512*2 = 131072
    unsigned short* dw1b = (unsigned short*)(ws + 983040);    // 512*64*2  = 65536
    unsigned short* dw2b = (unsigned short*)(ws + 1048576);   // 896*512*2 = 917504
    float* bias1  = (float*)(ws + 1966080);
    float* biasab = (float*)(ws + 1968128);
    float* biasd1 = (float*)(ws + 1970688);
    float* biasd2 = (float*)(ws + 1972736);
    unsigned short* h    = (unsigned short*)(ws + 2097152);   // [B][512] bf16 = 33.5MB
    unsigned short* pib  = (unsigned short*)(ws + 35651584);  // [B][64]  bf16 = 4.2MB
    unsigned short* hdb  = h;                                  // reuse h (dead after GEMM2/3)
    // peak ws = 39.85 MB

    // ---- prep ----
    cast_x<<<dim3(BATCH * 104 / 256), 256, 0, stream>>>(x, xb);
    prep_bt<<<dim3(512 * 832 / 256), 256, 0, stream>>>(
        enc_w1, enc_b1, w1b, bias1, 784, 500, 832, 512);
    prep_wab<<<dim3(256), 256, 0, stream>>>(w_alpha, w_beta, b_alpha, b_beta, wab, biasab);
    prep_bt<<<dim3(512 * 64 / 256), 256, 0, stream>>>(
        dec_w1, dec_b1, dw1b, biasd1, 50, 500, 64, 512);
    prep_bt<<<dim3(896 * 512 / 256), 256, 0, stream>>>(
        dec_w2, dec_b2, dw2b, biasd2, 500, 784, 512, 896);

    // ---- GEMM1: h = relu(xb @ enc_w1 + b1) ----
    mfma_gemm<0><<<dim3((512 / BN) * (BATCH / BM)), 256, 0, stream>>>(
        xb, w1b, bias1, h, 832, 832, 512, 500, 512 / BN);

    // ---- GEMM2/3: [alpha|beta] = softplus(h @ wab + b) ----
    mfma_gemm<1><<<dim3(BATCH / BM), 256, 0, stream>>>(
        h, wab, biasab, alpha, 512, 512, 0, 100, 1);

    // ---- sample: one wave per row ----
    sample_pi<<<dim3(BATCH * 64 / 256), 256, 0, stream>>>(
        u, alpha, alpha + (size_t)BATCH * 50, pib);

    // ---- GEMM4: hd = relu(pib @ dec_w1 + b) ----
    mfma_gemm<0><<<dim3((512 / BN) * (BATCH / BM)), 256, 0, stream>>>(
        pib, dw1b, biasd1, hdb, 64, 64, 512, 500, 512 / BN);

    // ---- GEMM5: recon = sigmoid(hd @ dec_w2 + b) (overwrites xb) ----
    mfma_gemm<2><<<dim3((896 / BN) * (BATCH / BM)), 256, 0, stream>>>(
        hdb, dw2b, biasd2, recon, 512, 512, 784, 784, 896 / BN);
}

// Round 6
// 174.241 us; speedup vs baseline: 1.0884x; 1.0884x over previous
//
#include <hip/hip_runtime.h>
#include <math.h>

// StickBreakingVAE forward, bf16-MFMA, single-buffered LDS + global_load_lds(B)
// + fused f32->bf16 A-staging for GEMM1 + XCD swizzle. B=32768, D=784, H=500, K=50.
// GEMM1: h   = relu(x @ enc_w1 + b)      A=f32 on-the-fly, K=832 N=512 (bf16, ws)
// GEMM2/3:   [alpha|beta] = softplus(h @ wab + b)  K=512 N=128 (f32 -> d_out)
// sample_pi: wave-per-row stick-breaking scan -> pib bf16 [B,64] (ws)
// GEMM4: hd  = relu(pib @ dec_w1 + b)    K=64  N=512  (bf16, reuses h region)
// GEMM5: rec = sigmoid(hd @ dec_w2 + b)  K=512 N=896  (f32 masked -> d_out)

typedef __bf16 bf16x8 __attribute__((ext_vector_type(8)));
typedef float f32x4 __attribute__((ext_vector_type(4)));

#define BATCH 32768
#define BM 128
#define BN 128
#define BK 64

__device__ __forceinline__ unsigned short bf16_bits(float f) {
    __bf16 b = (__bf16)f;
    return __builtin_bit_cast(unsigned short, b);
}

__device__ __forceinline__ void gll16(const unsigned short* src, unsigned short* ldsdst) {
    __builtin_amdgcn_global_load_lds(
        (const __attribute__((address_space(1))) unsigned int*)src,
        (__attribute__((address_space(3))) unsigned int*)ldsdst,
        16, 0, 0);
}

// MODE 0: relu -> bf16 C [ldc], full padded tile stored
// MODE 1: softplus -> alpha (gn<50) / beta (50<=gn<100) f32 compact [B,50] each
// MODE 2: sigmoid -> f32 C [B,Nreal], store only gn < Nreal
// AF32: A is f32 [M][lda], cast to bf16 during reg-staging (fused cast_x)
template<int MODE, bool AF32>
__global__ __launch_bounds__(256) void mfma_gemm(
    const void* __restrict__ Av,
    const unsigned short* __restrict__ Bt,  // [Npad][Kpad] bf16 (zero-padded)
    const float* __restrict__ bias,         // [Npad]
    void* __restrict__ Cv,
    int Kpad, int Kreal, int lda, int ldc, int Nreal, int nbx)
{
    __shared__ unsigned short As[BM * BK];   // linear row*64 + swizzled-granule*8
    __shared__ unsigned short Bs[BN * BK];

    // ---- chunked bijective XCD swizzle (T1, m204): same-A-panel blocks -> same XCD L2
    const int nwg = gridDim.x;
    const int orig = blockIdx.x;
    const int q = nwg >> 3, r8 = nwg & 7;
    const int xcd = orig & 7;
    const int chunkbase = (xcd < r8) ? xcd * (q + 1) : r8 * (q + 1) + (xcd - r8) * q;
    const int wgid = chunkbase + (orig >> 3);
    const int bn = wgid % nbx;               // n fastest within chunk -> A-panel L2 reuse
    const size_t block_m = (size_t)(wgid / nbx) * BM;
    const int block_n = bn * BN;

    const int tid = threadIdx.x;
    const int l = tid & 63;
    const int wid = tid >> 6;
    const int wr = wid >> 1, wc = wid & 1;

    const int lr = l & 15;   // fragment row-in-16
    const int kh = l >> 4;   // fragment k-granule (0..3)

    f32x4 acc[4][4] = {};

    for (int k0 = 0; k0 < Kpad; k0 += BK) {
        // ---- stage B first (async gll: loads fly while A does register work) ----
        #pragma unroll
        for (int i = 0; i < 4; ++i) {
            int chunk = wid * 4 + i;          // 16 chunks of 1KB each
            int gid = chunk * 64 + l;         // granule id 0..1023
            int r = gid >> 3;                 // tile row 0..127
            int kgs = (gid & 7) ^ (r & 7);    // swizzled source granule
            gll16(Bt + (size_t)(block_n + r) * Kpad + k0 + kgs * 8, Bs + chunk * 512);
        }
        // ---- stage A ----
        if (AF32) {
            // f32 source: coalesced float4 x2 per granule -> cvt -> swizzled ds_write
            const float* Af = (const float*)Av;
            #pragma unroll
            for (int i = 0; i < 4; ++i) {
                int gid = i * 256 + tid;      // granule id 0..1023
                int r = gid >> 3, kg = gid & 7;
                int gk = k0 + kg * 8;
                union { __bf16 b[8]; uint4 u4; } pk;
                if (gk < Kreal) {
                    const float4* p = (const float4*)(Af + (block_m + r) * (size_t)lda + gk);
                    float4 f0 = p[0], f1 = p[1];
                    pk.b[0] = (__bf16)f0.x; pk.b[1] = (__bf16)f0.y;
                    pk.b[2] = (__bf16)f0.z; pk.b[3] = (__bf16)f0.w;
                    pk.b[4] = (__bf16)f1.x; pk.b[5] = (__bf16)f1.y;
                    pk.b[6] = (__bf16)f1.z; pk.b[7] = (__bf16)f1.w;
                } else {
                    pk.u4 = make_uint4(0, 0, 0, 0);
                }
                *(uint4*)(As + r * 64 + ((kg ^ (r & 7)) * 8)) = pk.u4;
            }
        } else {
            const unsigned short* Ab = (const unsigned short*)Av;
            #pragma unroll
            for (int i = 0; i < 4; ++i) {
                int chunk = wid * 4 + i;
                int gid = chunk * 64 + l;
                int r = gid >> 3;
                int kgs = (gid & 7) ^ (r & 7);
                gll16(Ab + (block_m + r) * (size_t)lda + k0 + kgs * 8, As + chunk * 512);
            }
        }
        __syncthreads();   // drains vmcnt (gll) + lgkmcnt (ds_write)

        #pragma unroll
        for (int s = 0; s < 2; ++s) {
            bf16x8 af[4], bf[4];
            #pragma unroll
            for (int mi = 0; mi < 4; ++mi) {
                int row = wr * 64 + mi * 16 + lr;
                int g = (s * 4 + kh) ^ (row & 7);
                af[mi] = *(const bf16x8*)(As + row * 64 + g * 8);
            }
            #pragma unroll
            for (int ni = 0; ni < 4; ++ni) {
                int row = wc * 64 + ni * 16 + lr;
                int g = (s * 4 + kh) ^ (row & 7);
                bf[ni] = *(const bf16x8*)(Bs + row * 64 + g * 8);
            }
            #pragma unroll
            for (int mi = 0; mi < 4; ++mi)
                #pragma unroll
                for (int ni = 0; ni < 4; ++ni)
                    acc[mi][ni] = __builtin_amdgcn_mfma_f32_16x16x32_bf16(
                        af[mi], bf[ni], acc[mi][ni], 0, 0, 0);
        }
        __syncthreads();
    }

    // epilogue: C/D layout col=lane&15, row=(lane>>4)*4+j
    const int rg = (l >> 4) * 4;
    #pragma unroll
    for (int mi = 0; mi < 4; ++mi) {
        #pragma unroll
        for (int ni = 0; ni < 4; ++ni) {
            int gn = block_n + wc * 64 + ni * 16 + lr;
            float bs = bias[gn];
            #pragma unroll
            for (int j = 0; j < 4; ++j) {
                long gm = block_m + wr * 64 + mi * 16 + rg + j;
                float z = acc[mi][ni][j] + bs;
                if (MODE == 0) {
                    z = fmaxf(z, 0.f);
                    ((unsigned short*)Cv)[gm * ldc + gn] = bf16_bits(z);
                } else if (MODE == 1) {
                    z = (z > 0.f) ? z + __logf(1.f + __expf(-z))
                                  : __logf(1.f + __expf(z));
                    float* out = (float*)Cv;
                    if (gn < 50)       out[gm * 50 + gn] = z;
                    else if (gn < 100) out[(size_t)BATCH * 50 + gm * 50 + (gn - 50)] = z;
                } else {
                    if (gn < Nreal) {
                        // single-sided sigmoid: safe for all finite z
                        // (exp(-z)->inf => result->0, the correct limit)
                        z = __fdividef(1.f, 1.f + __expf(-z));
                        ((float*)Cv)[gm * Nreal + gn] = z;
                    }
                }
            }
        }
    }
}

// weight [Kr][Nr] f32 -> [Npad][Kpad] bf16 transposed, bias padded
__global__ __launch_bounds__(256) void prep_bt(
    const float* __restrict__ W, const float* __restrict__ bias,
    unsigned short* __restrict__ Bt, float* __restrict__ bpad,
    int Kr, int Nr, int Kpad, int Npad)
{
    int idx = blockIdx.x * 256 + threadIdx.x;
    if (idx >= Npad * Kpad) return;
    int n = idx / Kpad, k = idx - n * Kpad;
    float v = (n < Nr && k < Kr) ? W[(size_t)k * Nr + n] : 0.f;
    Bt[idx] = bf16_bits(v);
    if (k == 0) bpad[n] = (n < Nr) ? bias[n] : 0.f;
}

// [w_alpha | w_beta] -> [128][512] bf16 transposed
__global__ __launch_bounds__(256) void prep_wab(
    const float* __restrict__ Wa, const float* __restrict__ Wb,
    const float* __restrict__ ba, const float* __restrict__ bb,
    unsigned short* __restrict__ Bt, float* __restrict__ bpad)
{
    int idx = blockIdx.x * 256 + threadIdx.x;
    if (idx >= 128 * 512) return;
    int n = idx >> 9, k = idx & 511;
    float v = 0.f;
    if (k < 500) {
        if (n < 50)       v = Wa[(size_t)k * 50 + n];
        else if (n < 100) v = Wb[(size_t)k * 50 + (n - 50)];
    }
    Bt[idx] = bf16_bits(v);
    if (k == 0) bpad[n] = (n < 50) ? ba[n] : ((n < 100) ? bb[n - 50] : 0.f);
}

// Kumaraswamy sample + stick-breaking. One WAVE per row: lane k computes v_k,
// then 6-step shuffle prefix-product scan replaces the serial cumprod.
__global__ __launch_bounds__(256) void sample_pi(
    const float* __restrict__ u, const float* __restrict__ alpha,
    const float* __restrict__ beta, unsigned short* __restrict__ pib)
{
    int row = (blockIdx.x * 256 + threadIdx.x) >> 6;   // wave index = row
    int lane = threadIdx.x & 63;
    size_t base = (size_t)row * 50;

    float v = 0.f, w = 1.f;
    if (lane < 50) {
        float a = alpha[base + lane];
        float b = beta[base + lane];
        float uu = u[base + lane];
        float t = exp2f(__fdividef(log2f(uu), b));          // u^(1/beta)
        v = exp2f(__fdividef(log2f(1.f - t), a));           // (1-t)^(1/alpha)
        w = 1.f - v;
    }
    // inclusive prefix product of w across the wave
    float p = w;
    #pragma unroll
    for (int off = 1; off < 64; off <<= 1) {
        float t = __shfl_up(p, off, 64);
        if (lane >= off) p *= t;
    }
    // exclusive scan -> pi = v * prod_{j<k}(1-v_j)
    float ex = __shfl_up(p, 1, 64);
    if (lane == 0) ex = 1.f;
    float pi = v * ex;
    pib[(size_t)row * 64 + lane] = (lane < 50) ? bf16_bits(pi) : (unsigned short)0;
}

extern "C" void kernel_launch(void* const* d_in, const int* in_sizes, int n_in,
                              void* d_out, int out_size, void* d_ws, size_t ws_size,
                              hipStream_t stream) {
    const float* x       = (const float*)d_in[0];
    const float* u       = (const float*)d_in[1];
    const float* enc_w1  = (const float*)d_in[2];
    const float* enc_b1  = (const float*)d_in[3];
    const float* w_alpha = (const float*)d_in[4];
    const float* b_alpha = (const float*)d_in[5];
    const float* w_beta  = (const float*)d_in[6];
    const float* b_beta  = (const float*)d_in[7];
    const float* dec_w1  = (const float*)d_in[8];
    const float* dec_b1  = (const float*)d_in[9];
    const float* dec_w2  = (const float*)d_in[10];
    const float* dec_b2  = (const float*)d_in[11];

    const int D = 784;

    float* out   = (float*)d_out;
    float* recon = out;                              // [B,784] f32
    float* alpha = out + (size_t)BATCH * D;          // [B,50]; beta at +B*50

    // workspace layout
    char* ws = (char*)d_ws;
    unsigned short* w1b  = (unsigned short*)(ws);             // 512*832*2 = 851968
    unsigned short* wab  = (unsigned short*)(ws + 851968);    // 128*512*2 = 131072
    unsigned short* dw1b = (unsigned short*)(ws + 983040);    // 512*64*2  = 65536
    unsigned short* dw2b = (unsigned short*)(ws + 1048576);   // 896*512*2 = 917504
    float* bias1  = (float*)(ws + 1966080);
    float* biasab = (float*)(ws + 1968128);
    float* biasd1 = (float*)(ws + 1970688);
    float* biasd2 = (float*)(ws + 1972736);
    unsigned short* h    = (unsigned short*)(ws + 2097152);   // [B][512] bf16 = 33.5MB
    unsigned short* pib  = (unsigned short*)(ws + 35651584);  // [B][64]  bf16 = 4.2MB
    unsigned short* hdb  = h;                                  // reuse h (dead after GEMM2/3)
    // peak ws = 39.85 MB

    // ---- prep weights ----
    prep_bt<<<dim3(512 * 832 / 256), 256, 0, stream>>>(
        enc_w1, enc_b1, w1b, bias1, 784, 500, 832, 512);
    prep_wab<<<dim3(256), 256, 0, stream>>>(w_alpha, w_beta, b_alpha, b_beta, wab, biasab);
    prep_bt<<<dim3(512 * 64 / 256), 256, 0, stream>>>(
        dec_w1, dec_b1, dw1b, biasd1, 50, 500, 64, 512);
    prep_bt<<<dim3(896 * 512 / 256), 256, 0, stream>>>(
        dec_w2, dec_b2, dw2b, biasd2, 500, 784, 512, 896);

    // ---- GEMM1: h = relu(x @ enc_w1 + b1), fused f32->bf16 A-staging ----
    mfma_gemm<0, true><<<dim3((512 / BN) * (BATCH / BM)), 256, 0, stream>>>(
        x, w1b, bias1, h, 832, 784, 784, 512, 500, 512 / BN);

    // ---- GEMM2/3: [alpha|beta] = softplus(h @ wab + b) ----
    mfma_gemm<1, false><<<dim3(BATCH / BM), 256, 0, stream>>>(
        h, wab, biasab, alpha, 512, 512, 512, 0, 100, 1);

    // ---- sample: one wave per row ----
    sample_pi<<<dim3(BATCH * 64 / 256), 256, 0, stream>>>(
        u, alpha, alpha + (size_t)BATCH * 50, pib);

    // ---- GEMM4: hd = relu(pib @ dec_w1 + b) ----
    mfma_gemm<0, false><<<dim3((512 / BN) * (BATCH / BM)), 256, 0, stream>>>(
        pib, dw1b, biasd1, hdb, 64, 64, 64, 512, 500, 512 / BN);

    // ---- GEMM5: recon = sigmoid(hd @ dec_w2 + b) ----
    mfma_gemm<2, false><<<dim3((896 / BN) * (BATCH / BM)), 256, 0, stream>>>(
        hdb, dw2b, biasd2, recon, 512, 512, 512, 784, 784, 896 / BN);
}

// Round 7
// 161.764 us; speedup vs baseline: 1.1724x; 1.0771x over previous
//
#include <hip/hip_runtime.h>
#include <math.h>

// StickBreakingVAE forward, bf16-MFMA, single-buffered LDS + global_load_lds(B)
// + T14-pipelined f32->bf16 A-staging for GEMM1 + XCD swizzle.
// B=32768, D=784, H=500, K=50.
// GEMM1: h   = relu(x @ enc_w1 + b)      A=f32 prefetch-1-tile, K=832 N=512 (bf16, ws)
// GEMM2/3:   [alpha|beta] = softplus(h @ wab + b)  K=512 N=128 (f32 -> d_out)
// sample_pi: wave-per-row stick-breaking scan -> pib bf16 [B,64] (ws)
// GEMM4: hd  = relu(pib @ dec_w1 + b)    K=64  N=512  (bf16, reuses h region)
// GEMM5: rec = sigmoid(hd @ dec_w2 + b)  K=512 N=896  (f32 masked -> d_out)

typedef __bf16 bf16x8 __attribute__((ext_vector_type(8)));
typedef float f32x4 __attribute__((ext_vector_type(4)));

#define BATCH 32768
#define BM 128
#define BN 128
#define BK 64

__device__ __forceinline__ unsigned short bf16_bits(float f) {
    __bf16 b = (__bf16)f;
    return __builtin_bit_cast(unsigned short, b);
}

__device__ __forceinline__ void gll16(const unsigned short* src, unsigned short* ldsdst) {
    __builtin_amdgcn_global_load_lds(
        (const __attribute__((address_space(1))) unsigned int*)src,
        (__attribute__((address_space(3))) unsigned int*)ldsdst,
        16, 0, 0);
}

// MODE 0: relu -> bf16 C [ldc], full padded tile stored
// MODE 1: softplus -> alpha (gn<50) / beta (50<=gn<100) f32 compact [B,50] each
// MODE 2: sigmoid -> f32 C [B,Nreal], store only gn < Nreal
// AF32: A is f32 [M][lda]; reg-prefetch 1 K-tile ahead, cvt+ds_write late (T14)
template<int MODE, bool AF32>
__global__ __launch_bounds__(256) void mfma_gemm(
    const void* __restrict__ Av,
    const unsigned short* __restrict__ Bt,  // [Npad][Kpad] bf16 (zero-padded)
    const float* __restrict__ bias,         // [Npad]
    void* __restrict__ Cv,
    int Kpad, int Kreal, int lda, int ldc, int Nreal, int nbx)
{
    __shared__ unsigned short As[BM * BK];   // linear row*64 + swizzled-granule*8
    __shared__ unsigned short Bs[BN * BK];

    // ---- chunked bijective XCD swizzle (T1, m204): same-A-panel blocks -> same XCD L2
    const int nwg = gridDim.x;
    const int orig = blockIdx.x;
    const int q = nwg >> 3, r8 = nwg & 7;
    const int xcd = orig & 7;
    const int chunkbase = (xcd < r8) ? xcd * (q + 1) : r8 * (q + 1) + (xcd - r8) * q;
    const int wgid = chunkbase + (orig >> 3);
    const int bn = wgid % nbx;               // n fastest within chunk -> A-panel L2 reuse
    const size_t block_m = (size_t)(wgid / nbx) * BM;
    const int block_n = bn * BN;

    const int tid = threadIdx.x;
    const int l = tid & 63;
    const int wid = tid >> 6;
    const int wr = wid >> 1, wc = wid & 1;

    const int lr = l & 15;   // fragment row-in-16
    const int kh = l >> 4;   // fragment k-granule (0..3)

    f32x4 acc[4][4] = {};

    auto issueB = [&](int k0) {
        #pragma unroll
        for (int i = 0; i < 4; ++i) {
            int chunk = wid * 4 + i;          // 16 chunks of 1KB each
            int gid = chunk * 64 + l;         // granule id 0..1023
            int r = gid >> 3;                 // tile row 0..127
            int kgs = (gid & 7) ^ (r & 7);    // swizzled source granule
            gll16(Bt + (size_t)(block_n + r) * Kpad + k0 + kgs * 8, Bs + chunk * 512);
        }
    };

    auto compute = [&]() {
        #pragma unroll
        for (int s = 0; s < 2; ++s) {
            bf16x8 af[4], bf[4];
            #pragma unroll
            for (int mi = 0; mi < 4; ++mi) {
                int row = wr * 64 + mi * 16 + lr;
                int g = (s * 4 + kh) ^ (row & 7);
                af[mi] = *(const bf16x8*)(As + row * 64 + g * 8);
            }
            #pragma unroll
            for (int ni = 0; ni < 4; ++ni) {
                int row = wc * 64 + ni * 16 + lr;
                int g = (s * 4 + kh) ^ (row & 7);
                bf[ni] = *(const bf16x8*)(Bs + row * 64 + g * 8);
            }
            #pragma unroll
            for (int mi = 0; mi < 4; ++mi)
                #pragma unroll
                for (int ni = 0; ni < 4; ++ni)
                    acc[mi][ni] = __builtin_amdgcn_mfma_f32_16x16x32_bf16(
                        af[mi], bf[ni], acc[mi][ni], 0, 0, 0);
        }
    };

    if constexpr (AF32) {
        // ---- T14 pipeline: A regs prefetched 1 K-tile ahead ----
        const float* Af = (const float*)Av;
        float4 areg[8];
        bool aok[4];
        const int clampk = Kreal - 8;

        auto issueA = [&](int k0) {
            #pragma unroll
            for (int i = 0; i < 4; ++i) {
                int gid = i * 256 + tid;      // granule id 0..1023
                int r = gid >> 3, kg = gid & 7;
                int gk = k0 + kg * 8;
                int gkc = (gk <= clampk) ? gk : clampk;   // clamped: always 8 loads/wave... (2 dwordx4)
                const float4* p = (const float4*)(Af + (block_m + r) * (size_t)lda + gkc);
                areg[2 * i]     = p[0];
                areg[2 * i + 1] = p[1];
                aok[i] = (gk < Kreal);
            }
        };
        auto writeA = [&]() {
            #pragma unroll
            for (int i = 0; i < 4; ++i) {
                int gid = i * 256 + tid;
                int r = gid >> 3, kg = gid & 7;
                union { __bf16 b[8]; uint4 u4; } pk;
                float4 f0 = areg[2 * i], f1 = areg[2 * i + 1];
                if (aok[i]) {
                    pk.b[0] = (__bf16)f0.x; pk.b[1] = (__bf16)f0.y;
                    pk.b[2] = (__bf16)f0.z; pk.b[3] = (__bf16)f0.w;
                    pk.b[4] = (__bf16)f1.x; pk.b[5] = (__bf16)f1.y;
                    pk.b[6] = (__bf16)f1.z; pk.b[7] = (__bf16)f1.w;
                } else {
                    pk.u4 = make_uint4(0, 0, 0, 0);
                }
                *(uint4*)(As + r * 64 + ((kg ^ (r & 7)) * 8)) = pk.u4;
            }
        };

        const int nt = Kpad / BK;
        issueA(0);
        for (int t = 0; t < nt - 1; ++t) {
            issueB(t * BK);          // 4 gll in flight over the A-wait
            writeA();                // compiler waits A-regs(t) (vmcnt(4)), cvt, ds_write
            issueA((t + 1) * BK);    // 8 loads fly across the barrier + compute
            // wait only B-glls (oldest 4) + my ds_writes; keep 8 A-loads in flight
            asm volatile("s_waitcnt vmcnt(8) lgkmcnt(0)" ::: "memory");
            __builtin_amdgcn_sched_barrier(0);
            __builtin_amdgcn_s_barrier();
            compute();
            __builtin_amdgcn_s_barrier();   // all waves done reading before overwrite
        }
        issueB((nt - 1) * BK);
        writeA();
        asm volatile("s_waitcnt vmcnt(0) lgkmcnt(0)" ::: "memory");
        __builtin_amdgcn_sched_barrier(0);
        __builtin_amdgcn_s_barrier();
        compute();
    } else {
        // ---- plain single-buffered gll loop (proven r4 structure) ----
        const unsigned short* Ab = (const unsigned short*)Av;
        for (int k0 = 0; k0 < Kpad; k0 += BK) {
            issueB(k0);
            #pragma unroll
            for (int i = 0; i < 4; ++i) {
                int chunk = wid * 4 + i;
                int gid = chunk * 64 + l;
                int r = gid >> 3;
                int kgs = (gid & 7) ^ (r & 7);
                gll16(Ab + (block_m + r) * (size_t)lda + k0 + kgs * 8, As + chunk * 512);
            }
            __syncthreads();
            compute();
            __syncthreads();
        }
    }

    // epilogue: C/D layout col=lane&15, row=(lane>>4)*4+j
    const int rg = (l >> 4) * 4;
    #pragma unroll
    for (int mi = 0; mi < 4; ++mi) {
        #pragma unroll
        for (int ni = 0; ni < 4; ++ni) {
            int gn = block_n + wc * 64 + ni * 16 + lr;
            float bs = bias[gn];
            #pragma unroll
            for (int j = 0; j < 4; ++j) {
                long gm = block_m + wr * 64 + mi * 16 + rg + j;
                float z = acc[mi][ni][j] + bs;
                if (MODE == 0) {
                    z = fmaxf(z, 0.f);
                    ((unsigned short*)Cv)[gm * ldc + gn] = bf16_bits(z);
                } else if (MODE == 1) {
                    z = (z > 0.f) ? z + __logf(1.f + __expf(-z))
                                  : __logf(1.f + __expf(z));
                    float* out = (float*)Cv;
                    if (gn < 50)       out[gm * 50 + gn] = z;
                    else if (gn < 100) out[(size_t)BATCH * 50 + gm * 50 + (gn - 50)] = z;
                } else {
                    if (gn < Nreal) {
                        // single-sided sigmoid: safe for all finite z
                        z = __fdividef(1.f, 1.f + __expf(-z));
                        ((float*)Cv)[gm * Nreal + gn] = z;
                    }
                }
            }
        }
    }
}

// weight [Kr][Nr] f32 -> [Npad][Kpad] bf16 transposed, bias padded
__global__ __launch_bounds__(256) void prep_bt(
    const float* __restrict__ W, const float* __restrict__ bias,
    unsigned short* __restrict__ Bt, float* __restrict__ bpad,
    int Kr, int Nr, int Kpad, int Npad)
{
    int idx = blockIdx.x * 256 + threadIdx.x;
    if (idx >= Npad * Kpad) return;
    int n = idx / Kpad, k = idx - n * Kpad;
    float v = (n < Nr && k < Kr) ? W[(size_t)k * Nr + n] : 0.f;
    Bt[idx] = bf16_bits(v);
    if (k == 0) bpad[n] = (n < Nr) ? bias[n] : 0.f;
}

// [w_alpha | w_beta] -> [128][512] bf16 transposed
__global__ __launch_bounds__(256) void prep_wab(
    const float* __restrict__ Wa, const float* __restrict__ Wb,
    const float* __restrict__ ba, const float* __restrict__ bb,
    unsigned short* __restrict__ Bt, float* __restrict__ bpad)
{
    int idx = blockIdx.x * 256 + threadIdx.x;
    if (idx >= 128 * 512) return;
    int n = idx >> 9, k = idx & 511;
    float v = 0.f;
    if (k < 500) {
        if (n < 50)       v = Wa[(size_t)k * 50 + n];
        else if (n < 100) v = Wb[(size_t)k * 50 + (n - 50)];
    }
    Bt[idx] = bf16_bits(v);
    if (k == 0) bpad[n] = (n < 50) ? ba[n] : ((n < 100) ? bb[n - 50] : 0.f);
}

// Kumaraswamy sample + stick-breaking. One WAVE per row: lane k computes v_k,
// then 6-step shuffle prefix-product scan replaces the serial cumprod.
__global__ __launch_bounds__(256) void sample_pi(
    const float* __restrict__ u, const float* __restrict__ alpha,
    const float* __restrict__ beta, unsigned short* __restrict__ pib)
{
    int row = (blockIdx.x * 256 + threadIdx.x) >> 6;   // wave index = row
    int lane = threadIdx.x & 63;
    size_t base = (size_t)row * 50;

    float v = 0.f, w = 1.f;
    if (lane < 50) {
        float a = alpha[base + lane];
        float b = beta[base + lane];
        float uu = u[base + lane];
        float t = exp2f(__fdividef(log2f(uu), b));          // u^(1/beta)
        v = exp2f(__fdividef(log2f(1.f - t), a));           // (1-t)^(1/alpha)
        w = 1.f - v;
    }
    // inclusive prefix product of w across the wave
    float p = w;
    #pragma unroll
    for (int off = 1; off < 64; off <<= 1) {
        float t = __shfl_up(p, off, 64);
        if (lane >= off) p *= t;
    }
    // exclusive scan -> pi = v * prod_{j<k}(1-v_j)
    float ex = __shfl_up(p, 1, 64);
    if (lane == 0) ex = 1.f;
    float pi = v * ex;
    pib[(size_t)row * 64 + lane] = (lane < 50) ? bf16_bits(pi) : (unsigned short)0;
}

extern "C" void kernel_launch(void* const* d_in, const int* in_sizes, int n_in,
                              void* d_out, int out_size, void* d_ws, size_t ws_size,
                              hipStream_t stream) {
    const float* x       = (const float*)d_in[0];
    const float* u       = (const float*)d_in[1];
    const float* enc_w1  = (const float*)d_in[2];
    const float* enc_b1  = (const float*)d_in[3];
    const float* w_alpha = (const float*)d_in[4];
    const float* b_alpha = (const float*)d_in[5];
    const float* w_beta  = (const float*)d_in[6];
    const float* b_beta  = (const float*)d_in[7];
    const float* dec_w1  = (const float*)d_in[8];
    const float* dec_b1  = (const float*)d_in[9];
    const float* dec_w2  = (const float*)d_in[10];
    const float* dec_b2  = (const float*)d_in[11];

    const int D = 784;

    float* out   = (float*)d_out;
    float* recon = out;                              // [B,784] f32
    float* alpha = out + (size_t)BATCH * D;          // [B,50]; beta at +B*50

    // workspace layout
    char* ws = (char*)d_ws;
    unsigned short* w1b  = (unsigned short*)(ws);             // 512*832*2 = 851968
    unsigned short* wab  = (unsigned short*)(ws + 851968);    // 128*512*2 = 131072
    unsigned short* dw1b = (unsigned short*)(ws + 983040);    // 512*64*2  = 65536
    unsigned short* dw2b = (unsigned short*)(ws + 1048576);   // 896*512*2 = 917504
    float* bias1  = (float*)(ws + 1966080);
    float* biasab = (float*)(ws + 1968128);
    float* biasd1 = (float*)(ws + 1970688);
    float* biasd2 = (float*)(ws + 1972736);
    unsigned short* h    = (unsigned short*)(ws + 2097152);   // [B][512] bf16 = 33.5MB
    unsigned short* pib  = (unsigned short*)(ws + 35651584);  // [B][64]  bf16 = 4.2MB
    unsigned short* hdb  = h;                                  // reuse h (dead after GEMM2/3)
    // peak ws = 39.85 MB

    // ---- prep weights ----
    prep_bt<<<dim3(512 * 832 / 256), 256, 0, stream>>>(
        enc_w1, enc_b1, w1b, bias1, 784, 500, 832, 512);
    prep_wab<<<dim3(256), 256, 0, stream>>>(w_alpha, w_beta, b_alpha, b_beta, wab, biasab);
    prep_bt<<<dim3(512 * 64 / 256), 256, 0, stream>>>(
        dec_w1, dec_b1, dw1b, biasd1, 50, 500, 64, 512);
    prep_bt<<<dim3(896 * 512 / 256), 256, 0, stream>>>(
        dec_w2, dec_b2, dw2b, biasd2, 500, 784, 512, 896);

    // ---- GEMM1: h = relu(x @ enc_w1 + b1), T14-pipelined f32 A-staging ----
    mfma_gemm<0, true><<<dim3((512 / BN) * (BATCH / BM)), 256, 0, stream>>>(
        x, w1b, bias1, h, 832, 784, 784, 512, 500, 512 / BN);

    // ---- GEMM2/3: [alpha|beta] = softplus(h @ wab + b) ----
    mfma_gemm<1, false><<<dim3(BATCH / BM), 256, 0, stream>>>(
        h, wab, biasab, alpha, 512, 512, 512, 0, 100, 1);

    // ---- sample: one wave per row ----
    sample_pi<<<dim3(BATCH * 64 / 256), 256, 0, stream>>>(
        u, alpha, alpha + (size_t)BATCH * 50, pib);

    // ---- GEMM4: hd = relu(pib @ dec_w1 + b) ----
    mfma_gemm<0, false><<<dim3((512 / BN) * (BATCH / BM)), 256, 0, stream>>>(
        pib, dw1b, biasd1, hdb, 64, 64, 64, 512, 500, 512 / BN);

    // ---- GEMM5: recon = sigmoid(hd @ dec_w2 + b) ----
    mfma_gemm<2, false><<<dim3((896 / BN) * (BATCH / BM)), 256, 0, stream>>>(
        hdb, dw2b, biasd2, recon, 512, 512, 512, 784, 784, 896 / BN);
}

// Round 8
// 145.286 us; speedup vs baseline: 1.3053x; 1.1134x over previous
//
#include <hip/hip_runtime.h>
#include <math.h>

// StickBreakingVAE forward, bf16-MFMA, 8-wave blocks (64x32 per-wave tile for
// occupancy), single-buffered LDS + global_load_lds(B) + T14-pipelined f32->bf16
// A-staging for GEMM1 + XCD swizzle. B=32768, D=784, H=500, K=50.
// GEMM1: h   = relu(x @ enc_w1 + b)      A=f32 prefetch-1-tile, K=832 N=512 (bf16, ws)
// GEMM2/3:   [alpha|beta] = softplus(h @ wab + b)  K=512 N=128 (f32 -> d_out)
// sample_pi: wave-per-row stick-breaking scan -> pib bf16 [B,64] (ws)
// GEMM4: hd  = relu(pib @ dec_w1 + b)    K=64  N=512  (bf16, reuses h region)
// GEMM5: rec = sigmoid(hd @ dec_w2 + b)  K=512 N=896  (f32 masked -> d_out)

typedef __bf16 bf16x8 __attribute__((ext_vector_type(8)));
typedef float f32x4 __attribute__((ext_vector_type(4)));

#define BATCH 32768
#define BM 128
#define BN 128
#define BK 64
#define NTHR 512

__device__ __forceinline__ unsigned short bf16_bits(float f) {
    __bf16 b = (__bf16)f;
    return __builtin_bit_cast(unsigned short, b);
}

__device__ __forceinline__ void gll16(const unsigned short* src, unsigned short* ldsdst) {
    __builtin_amdgcn_global_load_lds(
        (const __attribute__((address_space(1))) unsigned int*)src,
        (__attribute__((address_space(3))) unsigned int*)ldsdst,
        16, 0, 0);
}

// MODE 0: relu -> bf16 C [ldc], full padded tile stored
// MODE 1: softplus -> alpha (gn<50) / beta (50<=gn<100) f32 compact [B,50] each
// MODE 2: sigmoid -> f32 C [B,Nreal], store only gn < Nreal
// AF32: A is f32 [M][lda]; reg-prefetch 1 K-tile ahead, cvt+ds_write late (T14)
template<int MODE, bool AF32>
__global__ __launch_bounds__(NTHR, 4) void mfma_gemm(
    const void* __restrict__ Av,
    const unsigned short* __restrict__ Bt,  // [Npad][Kpad] bf16 (zero-padded)
    const float* __restrict__ bias,         // [Npad]
    void* __restrict__ Cv,
    int Kpad, int Kreal, int lda, int ldc, int Nreal, int nbx)
{
    __shared__ unsigned short As[BM * BK];   // linear row*64 + swizzled-granule*8
    __shared__ unsigned short Bs[BN * BK];

    // ---- chunked bijective XCD swizzle (T1, m204): same-A-panel blocks -> same XCD L2
    const int nwg = gridDim.x;
    const int orig = blockIdx.x;
    const int q = nwg >> 3, r8 = nwg & 7;
    const int xcd = orig & 7;
    const int chunkbase = (xcd < r8) ? xcd * (q + 1) : r8 * (q + 1) + (xcd - r8) * q;
    const int wgid = chunkbase + (orig >> 3);
    const int bn = wgid % nbx;               // n fastest within chunk -> A-panel L2 reuse
    const size_t block_m = (size_t)(wgid / nbx) * BM;
    const int block_n = bn * BN;

    const int tid = threadIdx.x;
    const int l = tid & 63;
    const int wid = tid >> 6;                // 0..7
    const int wr = wid >> 2, wc = wid & 3;   // wave tile: 64 rows x 32 cols

    const int lr = l & 15;   // fragment row-in-16
    const int kh = l >> 4;   // fragment k-granule (0..3)

    f32x4 acc[4][2] = {};

    auto issueB = [&](int k0) {
        #pragma unroll
        for (int i = 0; i < 2; ++i) {
            int chunk = wid * 2 + i;          // 16 chunks of 1KB each
            int gid = chunk * 64 + l;         // granule id 0..1023
            int r = gid >> 3;                 // tile row 0..127
            int kgs = (gid & 7) ^ (r & 7);    // swizzled source granule
            gll16(Bt + (size_t)(block_n + r) * Kpad + k0 + kgs * 8, Bs + chunk * 512);
        }
    };

    auto compute = [&]() {
        #pragma unroll
        for (int s = 0; s < 2; ++s) {
            bf16x8 af[4], bf[2];
            #pragma unroll
            for (int mi = 0; mi < 4; ++mi) {
                int row = wr * 64 + mi * 16 + lr;
                int g = (s * 4 + kh) ^ (row & 7);
                af[mi] = *(const bf16x8*)(As + row * 64 + g * 8);
            }
            #pragma unroll
            for (int ni = 0; ni < 2; ++ni) {
                int row = wc * 32 + ni * 16 + lr;
                int g = (s * 4 + kh) ^ (row & 7);
                bf[ni] = *(const bf16x8*)(Bs + row * 64 + g * 8);
            }
            #pragma unroll
            for (int mi = 0; mi < 4; ++mi)
                #pragma unroll
                for (int ni = 0; ni < 2; ++ni)
                    acc[mi][ni] = __builtin_amdgcn_mfma_f32_16x16x32_bf16(
                        af[mi], bf[ni], acc[mi][ni], 0, 0, 0);
        }
    };

    if constexpr (AF32) {
        // ---- T14 pipeline: A regs prefetched 1 K-tile ahead (16 VGPR) ----
        const float* Af = (const float*)Av;
        float4 areg[4];
        bool aok[2];
        const int clampk = Kreal - 8;

        auto issueA = [&](int k0) {
            #pragma unroll
            for (int i = 0; i < 2; ++i) {
                int gid = i * NTHR + tid;     // granule id 0..1023
                int r = gid >> 3, kg = gid & 7;
                int gk = k0 + kg * 8;
                int gkc = (gk <= clampk) ? gk : clampk;   // clamped: count-exact loads
                const float4* p = (const float4*)(Af + (block_m + r) * (size_t)lda + gkc);
                areg[2 * i]     = p[0];
                areg[2 * i + 1] = p[1];
                aok[i] = (gk < Kreal);
            }
        };
        auto writeA = [&]() {
            #pragma unroll
            for (int i = 0; i < 2; ++i) {
                int gid = i * NTHR + tid;
                int r = gid >> 3, kg = gid & 7;
                union { __bf16 b[8]; uint4 u4; } pk;
                float4 f0 = areg[2 * i], f1 = areg[2 * i + 1];
                if (aok[i]) {
                    pk.b[0] = (__bf16)f0.x; pk.b[1] = (__bf16)f0.y;
                    pk.b[2] = (__bf16)f0.z; pk.b[3] = (__bf16)f0.w;
                    pk.b[4] = (__bf16)f1.x; pk.b[5] = (__bf16)f1.y;
                    pk.b[6] = (__bf16)f1.z; pk.b[7] = (__bf16)f1.w;
                } else {
                    pk.u4 = make_uint4(0, 0, 0, 0);
                }
                *(uint4*)(As + r * 64 + ((kg ^ (r & 7)) * 8)) = pk.u4;
            }
        };

        const int nt = Kpad / BK;
        issueA(0);
        for (int t = 0; t < nt - 1; ++t) {
            issueB(t * BK);          // 2 gll in flight over the A-wait
            writeA();                // compiler waits A-regs(t), cvt, ds_write
            issueA((t + 1) * BK);    // 4 loads fly across the barrier + compute
            // wait only B-glls (oldest 2) + my ds_writes; keep 4 A-loads in flight
            asm volatile("s_waitcnt vmcnt(4) lgkmcnt(0)" ::: "memory");
            __builtin_amdgcn_sched_barrier(0);
            __builtin_amdgcn_s_barrier();
            compute();
            __builtin_amdgcn_s_barrier();   // all waves done reading before overwrite
        }
        issueB((nt - 1) * BK);
        writeA();
        asm volatile("s_waitcnt vmcnt(0) lgkmcnt(0)" ::: "memory");
        __builtin_amdgcn_sched_barrier(0);
        __builtin_amdgcn_s_barrier();
        compute();
    } else {
        // ---- plain single-buffered gll loop (proven r4 structure) ----
        const unsigned short* Ab = (const unsigned short*)Av;
        for (int k0 = 0; k0 < Kpad; k0 += BK) {
            issueB(k0);
            #pragma unroll
            for (int i = 0; i < 2; ++i) {
                int chunk = wid * 2 + i;
                int gid = chunk * 64 + l;
                int r = gid >> 3;
                int kgs = (gid & 7) ^ (r & 7);
                gll16(Ab + (block_m + r) * (size_t)lda + k0 + kgs * 8, As + chunk * 512);
            }
            __syncthreads();
            compute();
            __syncthreads();
        }
    }

    // epilogue: C/D layout col=lane&15, row=(lane>>4)*4+j
    const int rg = (l >> 4) * 4;
    #pragma unroll
    for (int mi = 0; mi < 4; ++mi) {
        #pragma unroll
        for (int ni = 0; ni < 2; ++ni) {
            int gn = block_n + wc * 32 + ni * 16 + lr;
            float bs = bias[gn];
            #pragma unroll
            for (int j = 0; j < 4; ++j) {
                long gm = block_m + wr * 64 + mi * 16 + rg + j;
                float z = acc[mi][ni][j] + bs;
                if (MODE == 0) {
                    z = fmaxf(z, 0.f);
                    ((unsigned short*)Cv)[gm * ldc + gn] = bf16_bits(z);
                } else if (MODE == 1) {
                    z = (z > 0.f) ? z + __logf(1.f + __expf(-z))
                                  : __logf(1.f + __expf(z));
                    float* out = (float*)Cv;
                    if (gn < 50)       out[gm * 50 + gn] = z;
                    else if (gn < 100) out[(size_t)BATCH * 50 + gm * 50 + (gn - 50)] = z;
                } else {
                    if (gn < Nreal) {
                        // single-sided sigmoid: safe for all finite z
                        z = __fdividef(1.f, 1.f + __expf(-z));
                        ((float*)Cv)[gm * Nreal + gn] = z;
                    }
                }
            }
        }
    }
}

// weight [Kr][Nr] f32 -> [Npad][Kpad] bf16 transposed, bias padded
__global__ __launch_bounds__(256) void prep_bt(
    const float* __restrict__ W, const float* __restrict__ bias,
    unsigned short* __restrict__ Bt, float* __restrict__ bpad,
    int Kr, int Nr, int Kpad, int Npad)
{
    int idx = blockIdx.x * 256 + threadIdx.x;
    if (idx >= Npad * Kpad) return;
    int n = idx / Kpad, k = idx - n * Kpad;
    float v = (n < Nr && k < Kr) ? W[(size_t)k * Nr + n] : 0.f;
    Bt[idx] = bf16_bits(v);
    if (k == 0) bpad[n] = (n < Nr) ? bias[n] : 0.f;
}

// [w_alpha | w_beta] -> [128][512] bf16 transposed
__global__ __launch_bounds__(256) void prep_wab(
    const float* __restrict__ Wa, const float* __restrict__ Wb,
    const float* __restrict__ ba, const float* __restrict__ bb,
    unsigned short* __restrict__ Bt, float* __restrict__ bpad)
{
    int idx = blockIdx.x * 256 + threadIdx.x;
    if (idx >= 128 * 512) return;
    int n = idx >> 9, k = idx & 511;
    float v = 0.f;
    if (k < 500) {
        if (n < 50)       v = Wa[(size_t)k * 50 + n];
        else if (n < 100) v = Wb[(size_t)k * 50 + (n - 50)];
    }
    Bt[idx] = bf16_bits(v);
    if (k == 0) bpad[n] = (n < 50) ? ba[n] : ((n < 100) ? bb[n - 50] : 0.f);
}

// Kumaraswamy sample + stick-breaking. One WAVE per row: lane k computes v_k,
// then 6-step shuffle prefix-product scan replaces the serial cumprod.
__global__ __launch_bounds__(256) void sample_pi(
    const float* __restrict__ u, const float* __restrict__ alpha,
    const float* __restrict__ beta, unsigned short* __restrict__ pib)
{
    int row = (blockIdx.x * 256 + threadIdx.x) >> 6;   // wave index = row
    int lane = threadIdx.x & 63;
    size_t base = (size_t)row * 50;

    float v = 0.f, w = 1.f;
    if (lane < 50) {
        float a = alpha[base + lane];
        float b = beta[base + lane];
        float uu = u[base + lane];
        float t = exp2f(__fdividef(log2f(uu), b));          // u^(1/beta)
        v = exp2f(__fdividef(log2f(1.f - t), a));           // (1-t)^(1/alpha)
        w = 1.f - v;
    }
    // inclusive prefix product of w across the wave
    float p = w;
    #pragma unroll
    for (int off = 1; off < 64; off <<= 1) {
        float t = __shfl_up(p, off, 64);
        if (lane >= off) p *= t;
    }
    // exclusive scan -> pi = v * prod_{j<k}(1-v_j)
    float ex = __shfl_up(p, 1, 64);
    if (lane == 0) ex = 1.f;
    float pi = v * ex;
    pib[(size_t)row * 64 + lane] = (lane < 50) ? bf16_bits(pi) : (unsigned short)0;
}

extern "C" void kernel_launch(void* const* d_in, const int* in_sizes, int n_in,
                              void* d_out, int out_size, void* d_ws, size_t ws_size,
                              hipStream_t stream) {
    const float* x       = (const float*)d_in[0];
    const float* u       = (const float*)d_in[1];
    const float* enc_w1  = (const float*)d_in[2];
    const float* enc_b1  = (const float*)d_in[3];
    const float* w_alpha = (const float*)d_in[4];
    const float* b_alpha = (const float*)d_in[5];
    const float* w_beta  = (const float*)d_in[6];
    const float* b_beta  = (const float*)d_in[7];
    const float* dec_w1  = (const float*)d_in[8];
    const float* dec_b1  = (const float*)d_in[9];
    const float* dec_w2  = (const float*)d_in[10];
    const float* dec_b2  = (const float*)d_in[11];

    const int D = 784;

    float* out   = (float*)d_out;
    float* recon = out;                              // [B,784] f32
    float* alpha = out + (size_t)BATCH * D;          // [B,50]; beta at +B*50

    // workspace layout
    char* ws = (char*)d_ws;
    unsigned short* w1b  = (unsigned short*)(ws);             // 512*832*2 = 851968
    unsigned short* wab  = (unsigned short*)(ws + 851968);    // 128*512*2 = 131072
    unsigned short* dw1b = (unsigned short*)(ws + 983040);    // 512*64*2  = 65536
    unsigned short* dw2b = (unsigned short*)(ws + 1048576);   // 896*512*2 = 917504
    float* bias1  = (float*)(ws + 1966080);
    float* biasab = (float*)(ws + 1968128);
    float* biasd1 = (float*)(ws + 1970688);
    float* biasd2 = (float*)(ws + 1972736);
    unsigned short* h    = (unsigned short*)(ws + 2097152);   // [B][512] bf16 = 33.5MB
    unsigned short* pib  = (unsigned short*)(ws + 35651584);  // [B][64]  bf16 = 4.2MB
    unsigned short* hdb  = h;                                  // reuse h (dead after GEMM2/3)
    // peak ws = 39.85 MB

    // ---- prep weights ----
    prep_bt<<<dim3(512 * 832 / 256), 256, 0, stream>>>(
        enc_w1, enc_b1, w1b, bias1, 784, 500, 832, 512);
    prep_wab<<<dim3(256), 256, 0, stream>>>(w_alpha, w_beta, b_alpha, b_beta, wab, biasab);
    prep_bt<<<dim3(512 * 64 / 256), 256, 0, stream>>>(
        dec_w1, dec_b1, dw1b, biasd1, 50, 500, 64, 512);
    prep_bt<<<dim3(896 * 512 / 256), 256, 0, stream>>>(
        dec_w2, dec_b2, dw2b, biasd2, 500, 784, 512, 896);

    // ---- GEMM1: h = relu(x @ enc_w1 + b1), T14-pipelined f32 A-staging ----
    mfma_gemm<0, true><<<dim3((512 / BN) * (BATCH / BM)), NTHR, 0, stream>>>(
        x, w1b, bias1, h, 832, 784, 784, 512, 500, 512 / BN);

    // ---- GEMM2/3: [alpha|beta] = softplus(h @ wab + b) ----
    mfma_gemm<1, false><<<dim3(BATCH / BM), NTHR, 0, stream>>>(
        h, wab, biasab, alpha, 512, 512, 512, 0, 100, 1);

    // ---- sample: one wave per row ----
    sample_pi<<<dim3(BATCH * 64 / 256), 256, 0, stream>>>(
        u, alpha, alpha + (size_t)BATCH * 50, pib);

    // ---- GEMM4: hd = relu(pib @ dec_w1 + b) ----
    mfma_gemm<0, false><<<dim3((512 / BN) * (BATCH / BM)), NTHR, 0, stream>>>(
        pib, dw1b, biasd1, hdb, 64, 64, 64, 512, 500, 512 / BN);

    // ---- GEMM5: recon = sigmoid(hd @ dec_w2 + b) ----
    mfma_gemm<2, false><<<dim3((896 / BN) * (BATCH / BM)), NTHR, 0, stream>>>(
        hdb, dw2b, biasd2, recon, 512, 512, 512, 784, 784, 896 / BN);
}